// Round 5
// baseline (630.268 us; speedup 1.0000x reference)
//
#include <hip/hip_runtime.h>
#include <stdint.h>

using f32x4  = __attribute__((ext_vector_type(4))) float;
using f32x16 = __attribute__((ext_vector_type(16))) float;
using f16x8  = __attribute__((ext_vector_type(8))) _Float16;

#define NB  16
#define NC  256
#define NC2 128
#define NN  4096
#define TILE_B 49152   // 48 KB per 64-key tile: K 16K (64x256B swz) + V 32K (256x128B swz)

__device__ __forceinline__ unsigned int pk2(float a, float b) {
    auto h = __builtin_amdgcn_cvt_pkrtz(a, b);   // __fp16 ext_vector(2)
    return __builtin_bit_cast(unsigned int, h);
}

__device__ __forceinline__ f16x8 pack8(f32x4 a, f32x4 b) {
    union { unsigned int w[4]; f16x8 v; } u;
    u.w[0] = pk2(a[0], a[1]); u.w[1] = pk2(a[2], a[3]);
    u.w[2] = pk2(b[0], b[1]); u.w[3] = pk2(b[2], b[3]);
    return u.v;
}

__device__ __forceinline__ void gload16(const void* g, void* l) {
    __builtin_amdgcn_global_load_lds(
        (const __attribute__((address_space(1))) unsigned int*)g,
        (__attribute__((address_space(3))) unsigned int*)l, 16, 0, 0);
}

// ---------------------------------------------------------------------------
// Phase 1: 1x1-conv projections as MFMA f16 GEMM (K=256 reduction).
// Grid: 16 b x 4 o-units (Q | K | V-lo | V-hi) x 32 n-tiles = 2048 blocks.
// Block: 4 waves, each 64o x 64n (2x2 subtiles of 32x32x16 MFMA).
// No LDS: W A-frags from f32x4 loads + cvt; X B-frags from 8 coalesced
// scalar f32 loads (stride NN).
// Outputs (same image as round 4, attn untouched):
//  - Q: linear f16 [b][n][128]            (mfma(W,X): o in regs -> 8B o-pack)
//  - K: pre-swizzled tile image rows n    (mfma(W,X): 8B o-pack within granule)
//  - V: pre-swizzled tile image rows o    (mfma(X,W): n in regs -> 8B n-pack)
// ---------------------------------------------------------------------------
__global__ __launch_bounds__(256, 4) void qkv_kernel(
    const float* __restrict__ x, const float* __restrict__ y,
    const float* __restrict__ Wq, const float* __restrict__ bq,
    const float* __restrict__ Wk, const float* __restrict__ bk,
    const float* __restrict__ Wv, const float* __restrict__ bv,
    unsigned short* __restrict__ Qf, char* __restrict__ KV)
{
    const int bid   = blockIdx.x;
    const int ntile = bid & 31;
    const int obt   = (bid >> 5) & 3;
    const int bb    = bid >> 7;
    const int nblk  = ntile * 128;

    const float* src  = (obt == 0) ? x : y;
    const float* W    = (obt == 0) ? Wq : ((obt == 1) ? Wk : (Wv + (obt == 2 ? 0 : 128) * NC));
    const float* bias = (obt == 0) ? bq : ((obt == 1) ? bk : (bv + (obt == 2 ? 0 : 128)));

    const int t    = threadIdx.x;
    const int lane = t & 63;
    const int wid  = t >> 6;
    const int wo   = (wid & 1) * 64;
    const int wn   = (wid >> 1) * 64;
    const int l31  = lane & 31;
    const int s    = lane >> 5;

    f32x16 acc[2][2];
    #pragma unroll
    for (int a = 0; a < 2; ++a)
        #pragma unroll
        for (int bc = 0; bc < 2; ++bc) acc[a][bc] = (f32x16)(0.0f);

    const float* srcb = src + (size_t)bb * NC * NN;

    #pragma unroll 4
    for (int ks = 0; ks < 16; ++ks) {
        const int c0 = ks * 16 + s * 8;
        f16x8 wf[2], xf[2];
        #pragma unroll
        for (int a = 0; a < 2; ++a) {
            const float* wr = W + (size_t)(wo + a * 32 + l31) * NC + c0;
            wf[a] = pack8(*(const f32x4*)wr, *(const f32x4*)(wr + 4));
        }
        #pragma unroll
        for (int bc = 0; bc < 2; ++bc) {
            const float* xc = srcb + (size_t)c0 * NN + nblk + wn + bc * 32 + l31;
            f32x4 v0, v1;
            v0[0] = xc[0*NN]; v0[1] = xc[1*NN]; v0[2] = xc[2*NN]; v0[3] = xc[3*NN];
            v1[0] = xc[4*NN]; v1[1] = xc[5*NN]; v1[2] = xc[6*NN]; v1[3] = xc[7*NN];
            xf[bc] = pack8(v0, v1);
        }
        if (obt < 2) {
            #pragma unroll
            for (int a = 0; a < 2; ++a)
                #pragma unroll
                for (int bc = 0; bc < 2; ++bc)
                    acc[a][bc] = __builtin_amdgcn_mfma_f32_32x32x16_f16(
                        wf[a], xf[bc], acc[a][bc], 0, 0, 0);
        } else {
            #pragma unroll
            for (int a = 0; a < 2; ++a)
                #pragma unroll
                for (int bc = 0; bc < 2; ++bc)
                    acc[a][bc] = __builtin_amdgcn_mfma_f32_32x32x16_f16(
                        xf[bc], wf[a], acc[a][bc], 0, 0, 0);
        }
    }

    if (obt < 2) {
        // D[o via regs][n via lane]; rows o = wo+a*32+(r&3)+8*(r>>2)+4*s
        #pragma unroll
        for (int a = 0; a < 2; ++a) {
            #pragma unroll
            for (int bc = 0; bc < 2; ++bc) {
                const int n = nblk + wn + bc * 32 + l31;
                #pragma unroll
                for (int g = 0; g < 4; ++g) {
                    const int o0 = wo + a * 32 + 8 * g + 4 * s;
                    const f32x4 bv4 = *(const f32x4*)(bias + o0);
                    union { unsigned int w[2]; uint2 u2; } pk;
                    pk.w[0] = pk2(acc[a][bc][g*4+0] + bv4[0], acc[a][bc][g*4+1] + bv4[1]);
                    pk.w[1] = pk2(acc[a][bc][g*4+2] + bv4[2], acc[a][bc][g*4+3] + bv4[3]);
                    if (obt == 0) {
                        *(uint2*)(Qf + ((size_t)bb*NN + n)*NC2 + o0) = pk.u2;
                    } else {
                        char* kvt = KV + (size_t)(bb*64 + (n >> 6)) * TILE_B;
                        const int nr = n & 63;
                        const int dst = nr*256 + ((((o0 >> 3) << 4)) ^ ((nr & 7) << 4)) + (o0 & 7) * 2;
                        *(uint2*)(kvt + dst) = pk.u2;
                    }
                }
            }
        }
    } else {
        // D[n via regs][o via lane]; o = (obt-2)*128 + wo + a*32 + l31
        #pragma unroll
        for (int a = 0; a < 2; ++a) {
            const int o = (obt - 2) * 128 + wo + a * 32 + l31;
            const float bvo = bias[wo + a * 32 + l31];
            #pragma unroll
            for (int bc = 0; bc < 2; ++bc) {
                #pragma unroll
                for (int g = 0; g < 4; ++g) {
                    const int nb0 = nblk + wn + bc * 32 + 8 * g + 4 * s;
                    char* kvt = KV + (size_t)(bb*64 + (nb0 >> 6)) * TILE_B + 16384;
                    const int nr = nb0 & 63;
                    union { unsigned int w[2]; uint2 u2; } pk;
                    pk.w[0] = pk2(acc[a][bc][g*4+0] + bvo, acc[a][bc][g*4+1] + bvo);
                    pk.w[1] = pk2(acc[a][bc][g*4+2] + bvo, acc[a][bc][g*4+3] + bvo);
                    const int dst = o*128 + ((((nr >> 3) << 4)) ^ ((o & 7) << 4)) + (nr & 7) * 2;
                    *(uint2*)(kvt + dst) = pk.u2;
                }
            }
        }
    }
}

// ---------------------------------------------------------------------------
// Phase 2: flash attention (UNCHANGED from round 4).
// ---------------------------------------------------------------------------
__global__ __launch_bounds__(256, 2) void attn_kernel(
    const unsigned short* __restrict__ Qf, const char* __restrict__ KV,
    const float* __restrict__ yg, const float* __restrict__ gamma,
    float* __restrict__ outp)
{
    __shared__ __align__(16) char tile[TILE_B];

    const int bid = ((blockIdx.x & 7) << 6) + (blockIdx.x >> 3);
    const int bb = bid >> 5;
    const int m0 = (bid & 31) * 128;
    const int t    = threadIdx.x;
    const int lane = t & 63;
    const int wv   = t >> 6;
    const int qcol = lane & 31;
    const int s    = lane >> 5;

    f16x8 qf[8];
    {
        const char* qrow = (const char*)Qf +
            (((size_t)bb*NN + m0 + wv*32 + qcol) * NC2) * 2;
        #pragma unroll
        for (int ks = 0; ks < 8; ++ks)
            qf[ks] = *(const f16x8*)(qrow + ks*32 + s*16);
    }

    f32x16 acc[8];
    #pragma unroll
    for (int ob = 0; ob < 8; ++ob) acc[ob] = (f32x16)(0.0f);
    float m_run = -3.0e38f, l_run = 0.0f;

    const char* kvb = KV + (size_t)bb * 64 * TILE_B;

    #pragma unroll
    for (int i = 0; i < 12; ++i)
        gload16(kvb + ((i*256 + t) << 4), tile + ((i*256 + wv*64) << 4));

    #pragma unroll 1
    for (int it = 0; it < 64; ++it) {
        asm volatile("s_waitcnt vmcnt(0)" ::: "memory");
        __syncthreads();

        #pragma unroll
        for (int kb = 0; kb < 2; ++kb) {
            f32x16 sS = (f32x16)(0.0f);
            const int key = kb*32 + qcol;
            const int rb  = key*256;
            const int sw  = (key&7) << 4;
            #pragma unroll
            for (int ks = 0; ks < 8; ++ks) {
                f16x8 kf = *(const f16x8*)(tile + rb + ((ks*32 + s*16) ^ sw));
                sS = __builtin_amdgcn_mfma_f32_32x32x16_f16(kf, qf[ks], sS, 0, 0, 0);
            }

            float pmax = fmaxf(fmaxf(fmaxf(sS[0], sS[1]), fmaxf(sS[2], sS[3])),
                               fmaxf(fmaxf(sS[4], sS[5]), fmaxf(sS[6], sS[7])));
            pmax = fmaxf(pmax,
                   fmaxf(fmaxf(fmaxf(sS[8], sS[9]), fmaxf(sS[10], sS[11])),
                         fmaxf(fmaxf(sS[12], sS[13]), fmaxf(sS[14], sS[15]))));
            pmax = fmaxf(pmax, __shfl_xor(pmax, 32));
            if (__any(pmax > m_run + 8.0f)) {
                const float mn = fmaxf(m_run, pmax);
                const float sc = __expf(m_run - mn);
                m_run = mn; l_run *= sc;
                #pragma unroll
                for (int ob = 0; ob < 8; ++ob)
                    #pragma unroll
                    for (int r = 0; r < 16; ++r) acc[ob][r] *= sc;
            }
            float p[16];
            float rs = 0.f;
            #pragma unroll
            for (int r = 0; r < 16; ++r) {
                p[r] = __expf(sS[r] - m_run);
                rs += p[r];
            }
            rs += __shfl_xor(rs, 32);
            l_run += rs;

            f16x8 pb0, pb1;
            #pragma unroll
            for (int ks2 = 0; ks2 < 2; ++ks2) {
                unsigned int pA0, pA1, pB0, pB1;
                if (ks2 == 0) {
                    pA0 = pk2(p[0], p[1]);  pA1 = pk2(p[2], p[3]);
                    pB0 = pk2(p[4], p[5]);  pB1 = pk2(p[6], p[7]);
                } else {
                    pA0 = pk2(p[8], p[9]);  pA1 = pk2(p[10], p[11]);
                    pB0 = pk2(p[12], p[13]); pB1 = pk2(p[14], p[15]);
                }
                const unsigned int lv0 = s ? pB0 : pA0;
                const unsigned int lv1 = s ? pB1 : pA1;
                const unsigned int sd0 = s ? pA0 : pB0;
                const unsigned int sd1 = s ? pA1 : pB1;
                const unsigned int rv0 = (unsigned int)__shfl_xor((int)sd0, 32);
                const unsigned int rv1 = (unsigned int)__shfl_xor((int)sd1, 32);
                union { unsigned int w[4]; f16x8 v; } u;
                u.w[0] = s ? rv0 : lv0;
                u.w[1] = s ? rv1 : lv1;
                u.w[2] = s ? lv0 : rv0;
                u.w[3] = s ? lv1 : rv1;
                if (ks2 == 0) pb0 = u.v; else pb1 = u.v;
            }

            #pragma unroll
            for (int ks2 = 0; ks2 < 2; ++ks2) {
                const int colb = kb*64 + ks2*32 + s*16;
                const f16x8 pbx = ks2 ? pb1 : pb0;
                #pragma unroll
                for (int ob = 0; ob < 8; ++ob) {
                    const int o = ob*32 + qcol;
                    f16x8 vf = *(const f16x8*)(tile + 16384 + o*128 +
                                               (colb ^ ((o&7)<<4)));
                    acc[ob] = __builtin_amdgcn_mfma_f32_32x32x16_f16(vf, pbx, acc[ob], 0, 0, 0);
                }
            }
        }

        __syncthreads();
        if (it < 63) {
            const char* src = kvb + (size_t)(it+1) * TILE_B;
            #pragma unroll
            for (int i = 0; i < 12; ++i)
                gload16(src + ((i*256 + t) << 4), tile + ((i*256 + wv*64) << 4));
        }
    }

    const float ga   = gamma[0];
    const float invl = 1.0f / l_run;
    const int n = m0 + wv*32 + qcol;
    #pragma unroll
    for (int ob = 0; ob < 8; ++ob) {
        #pragma unroll
        for (int r = 0; r < 16; ++r) {
            const int o = ob*32 + (r&3) + 8*(r>>2) + 4*s;
            const size_t a = ((size_t)(bb*NC + o))*NN + n;
            outp[a] = fmaf(acc[ob][r]*invl, ga, yg[a]);
        }
    }
}

extern "C" void kernel_launch(void* const* d_in, const int* in_sizes, int n_in,
                              void* d_out, int out_size, void* d_ws, size_t ws_size,
                              hipStream_t stream) {
    (void)in_sizes; (void)n_in; (void)out_size; (void)ws_size;
    const float* x     = (const float*)d_in[0];
    const float* y     = (const float*)d_in[1];
    const float* Wq    = (const float*)d_in[2];
    const float* bq    = (const float*)d_in[3];
    const float* Wk    = (const float*)d_in[4];
    const float* bk    = (const float*)d_in[5];
    const float* Wv    = (const float*)d_in[6];
    const float* bv    = (const float*)d_in[7];
    const float* gamma = (const float*)d_in[8];
    float* out = (float*)d_out;

    unsigned short* Qf = (unsigned short*)d_ws;              // 16 MB f16
    char* KV = (char*)(Qf + (size_t)NB*NN*NC2);              // 48 MB tiles

    qkv_kernel<<<dim3(2048), dim3(256), 0, stream>>>(
        x, y, Wq, bq, Wk, bk, Wv, bv, Qf, KV);
    attn_kernel<<<dim3(512), dim3(256), 0, stream>>>(
        Qf, KV, y, gamma, out);
}

// Round 6
// 319.562 us; speedup vs baseline: 1.9723x; 1.9723x over previous
//
#include <hip/hip_runtime.h>
#include <stdint.h>

using f32x4  = __attribute__((ext_vector_type(4))) float;
using f32x16 = __attribute__((ext_vector_type(16))) float;
using f16x8  = __attribute__((ext_vector_type(8))) _Float16;

#define NB  16
#define NC  256
#define NC2 128
#define NN  4096
#define TILE_B 49152   // 48 KB per 64-key tile: K 16K (64x256B swz) + V 32K (256x128B swz)

__device__ __forceinline__ unsigned int pk2(float a, float b) {
    auto h = __builtin_amdgcn_cvt_pkrtz(a, b);   // __fp16 ext_vector(2)
    return __builtin_bit_cast(unsigned int, h);
}

__device__ __forceinline__ f16x8 pack8(f32x4 a, f32x4 b) {
    union { unsigned int w[4]; f16x8 v; } u;
    u.w[0] = pk2(a[0], a[1]); u.w[1] = pk2(a[2], a[3]);
    u.w[2] = pk2(b[0], b[1]); u.w[3] = pk2(b[2], b[3]);
    return u.v;
}

__device__ __forceinline__ void gload16(const void* g, void* l) {
    __builtin_amdgcn_global_load_lds(
        (const __attribute__((address_space(1))) unsigned int*)g,
        (__attribute__((address_space(3))) unsigned int*)l, 16, 0, 0);
}

// ---------------------------------------------------------------------------
// Phase 1: 1x1-conv projections as MFMA f16 GEMM, LDS-staged epilogue.
// Grid: 16 b x 64 n-tiles = 1024 blocks; block computes ALL of Q/K/V for its
// 64-n slice into a 64 KB LDS image [K 16K | V 32K | Q 16K] (same swizzled
// image math as round 5, retargeted at LDS), then streams it out with
// fully-coalesced uint4 stores. KV region is bit-exact the attn tile image;
// Q is copied through the involutive inverse swizzle so global Q is linear.
// Pass 1: waves 0-1 Q (src x), waves 2-3 K (src y), mfma(W,X) o-in-regs.
// Pass 2: all waves V (src y), mfma(X,W) n-in-regs.
// ---------------------------------------------------------------------------
__global__ __launch_bounds__(256, 2) void qkv_kernel(
    const float* __restrict__ x, const float* __restrict__ y,
    const float* __restrict__ Wq, const float* __restrict__ bq,
    const float* __restrict__ Wk, const float* __restrict__ bk,
    const float* __restrict__ Wv, const float* __restrict__ bv,
    unsigned short* __restrict__ Qf, char* __restrict__ KV)
{
    __shared__ __align__(16) char lds[65536];

    const int bid   = blockIdx.x;
    const int ntile = bid & 63;
    const int bb    = bid >> 6;
    const int nblk  = ntile * 64;

    const int t    = threadIdx.x;
    const int lane = t & 63;
    const int wid  = t >> 6;
    const int l31  = lane & 31;
    const int s    = lane >> 5;

    // ---------------- pass 1: Q (waves 0-1) / K (waves 2-3) ----------------
    {
        const bool isQ = (wid < 2);
        const float* srcb = (isQ ? x : y) + (size_t)bb * NC * NN;
        const float* W    = isQ ? Wq : Wk;
        const float* bias = isQ ? bq : bk;
        const int wo = (wid & 1) * 64;
        const int base = isQ ? 49152 : 0;

        f32x16 acc[2][2];
        #pragma unroll
        for (int a = 0; a < 2; ++a)
            #pragma unroll
            for (int bc = 0; bc < 2; ++bc) acc[a][bc] = (f32x16)(0.0f);

        #pragma unroll 4
        for (int ks = 0; ks < 16; ++ks) {
            const int c0 = ks * 16 + s * 8;
            f16x8 wf[2], xf[2];
            #pragma unroll
            for (int a = 0; a < 2; ++a) {
                const float* wr = W + (size_t)(wo + a * 32 + l31) * NC + c0;
                wf[a] = pack8(*(const f32x4*)wr, *(const f32x4*)(wr + 4));
            }
            #pragma unroll
            for (int bc = 0; bc < 2; ++bc) {
                const float* xc = srcb + (size_t)c0 * NN + nblk + bc * 32 + l31;
                f32x4 v0, v1;
                v0[0] = xc[0*NN]; v0[1] = xc[1*NN]; v0[2] = xc[2*NN]; v0[3] = xc[3*NN];
                v1[0] = xc[4*NN]; v1[1] = xc[5*NN]; v1[2] = xc[6*NN]; v1[3] = xc[7*NN];
                xf[bc] = pack8(v0, v1);
            }
            #pragma unroll
            for (int a = 0; a < 2; ++a)
                #pragma unroll
                for (int bc = 0; bc < 2; ++bc)
                    acc[a][bc] = __builtin_amdgcn_mfma_f32_32x32x16_f16(
                        wf[a], xf[bc], acc[a][bc], 0, 0, 0);
        }

        #pragma unroll
        for (int a = 0; a < 2; ++a) {
            #pragma unroll
            for (int bc = 0; bc < 2; ++bc) {
                const int nr = bc * 32 + l31;
                #pragma unroll
                for (int g = 0; g < 4; ++g) {
                    const int o0 = wo + a * 32 + 8 * g + 4 * s;
                    const f32x4 bv4 = *(const f32x4*)(bias + o0);
                    union { unsigned int w[2]; uint2 u2; } pk;
                    pk.w[0] = pk2(acc[a][bc][g*4+0] + bv4[0], acc[a][bc][g*4+1] + bv4[1]);
                    pk.w[1] = pk2(acc[a][bc][g*4+2] + bv4[2], acc[a][bc][g*4+3] + bv4[3]);
                    const int dst = base + nr*256 +
                        (((o0 >> 3) << 4) ^ ((nr & 7) << 4)) + (o0 & 7) * 2;
                    *(uint2*)(lds + dst) = pk.u2;
                }
            }
        }
    }

    // ---------------- pass 2: V (all waves, swapped mfma) ----------------
    {
        const float* srcb = y + (size_t)bb * NC * NN;
        const int wo = wid * 64;

        f32x16 acc[2][2];
        #pragma unroll
        for (int a = 0; a < 2; ++a)
            #pragma unroll
            for (int bc = 0; bc < 2; ++bc) acc[a][bc] = (f32x16)(0.0f);

        #pragma unroll 4
        for (int ks = 0; ks < 16; ++ks) {
            const int c0 = ks * 16 + s * 8;
            f16x8 wf[2], xf[2];
            #pragma unroll
            for (int a = 0; a < 2; ++a) {
                const float* wr = Wv + (size_t)(wo + a * 32 + l31) * NC + c0;
                wf[a] = pack8(*(const f32x4*)wr, *(const f32x4*)(wr + 4));
            }
            #pragma unroll
            for (int bc = 0; bc < 2; ++bc) {
                const float* xc = srcb + (size_t)c0 * NN + nblk + bc * 32 + l31;
                f32x4 v0, v1;
                v0[0] = xc[0*NN]; v0[1] = xc[1*NN]; v0[2] = xc[2*NN]; v0[3] = xc[3*NN];
                v1[0] = xc[4*NN]; v1[1] = xc[5*NN]; v1[2] = xc[6*NN]; v1[3] = xc[7*NN];
                xf[bc] = pack8(v0, v1);
            }
            #pragma unroll
            for (int a = 0; a < 2; ++a)
                #pragma unroll
                for (int bc = 0; bc < 2; ++bc)
                    acc[a][bc] = __builtin_amdgcn_mfma_f32_32x32x16_f16(
                        xf[bc], wf[a], acc[a][bc], 0, 0, 0);
        }

        #pragma unroll
        for (int a = 0; a < 2; ++a) {
            const int o = wo + a * 32 + l31;
            const float bvo = bv[o];
            #pragma unroll
            for (int bc = 0; bc < 2; ++bc) {
                #pragma unroll
                for (int g = 0; g < 4; ++g) {
                    const int nr = bc * 32 + 8 * g + 4 * s;
                    union { unsigned int w[2]; uint2 u2; } pk;
                    pk.w[0] = pk2(acc[a][bc][g*4+0] + bvo, acc[a][bc][g*4+1] + bvo);
                    pk.w[1] = pk2(acc[a][bc][g*4+2] + bvo, acc[a][bc][g*4+3] + bvo);
                    const int dst = 16384 + o*128 +
                        (((nr >> 3) << 4) ^ ((o & 7) << 4)) + (nr & 7) * 2;
                    *(uint2*)(lds + dst) = pk.u2;
                }
            }
        }
    }

    __syncthreads();

    // ---------------- coalesced copy-out ----------------
    char* kvt = KV + (size_t)(bb*64 + ntile) * TILE_B;
    #pragma unroll
    for (int i = 0; i < 12; ++i) {
        const int off = (i*256 + t) * 16;
        *(uint4*)(kvt + off) = *(const uint4*)(lds + off);
    }
    char* qg = (char*)Qf + ((size_t)(bb*NN + nblk)) * NC2 * 2;
    #pragma unroll
    for (int i = 0; i < 4; ++i) {
        const int g = (i*256 + t) * 16;
        const int sidx = 49152 + (g ^ (((g >> 8) & 7) << 4));
        *(uint4*)(qg + g) = *(const uint4*)(lds + sidx);
    }
}

// ---------------------------------------------------------------------------
// Phase 2: flash attention (UNCHANGED from round 4).
// ---------------------------------------------------------------------------
__global__ __launch_bounds__(256, 2) void attn_kernel(
    const unsigned short* __restrict__ Qf, const char* __restrict__ KV,
    const float* __restrict__ yg, const float* __restrict__ gamma,
    float* __restrict__ outp)
{
    __shared__ __align__(16) char tile[TILE_B];

    const int bid = ((blockIdx.x & 7) << 6) + (blockIdx.x >> 3);
    const int bb = bid >> 5;
    const int m0 = (bid & 31) * 128;
    const int t    = threadIdx.x;
    const int lane = t & 63;
    const int wv   = t >> 6;
    const int qcol = lane & 31;
    const int s    = lane >> 5;

    f16x8 qf[8];
    {
        const char* qrow = (const char*)Qf +
            (((size_t)bb*NN + m0 + wv*32 + qcol) * NC2) * 2;
        #pragma unroll
        for (int ks = 0; ks < 8; ++ks)
            qf[ks] = *(const f16x8*)(qrow + ks*32 + s*16);
    }

    f32x16 acc[8];
    #pragma unroll
    for (int ob = 0; ob < 8; ++ob) acc[ob] = (f32x16)(0.0f);
    float m_run = -3.0e38f, l_run = 0.0f;

    const char* kvb = KV + (size_t)bb * 64 * TILE_B;

    #pragma unroll
    for (int i = 0; i < 12; ++i)
        gload16(kvb + ((i*256 + t) << 4), tile + ((i*256 + wv*64) << 4));

    #pragma unroll 1
    for (int it = 0; it < 64; ++it) {
        asm volatile("s_waitcnt vmcnt(0)" ::: "memory");
        __syncthreads();

        #pragma unroll
        for (int kb = 0; kb < 2; ++kb) {
            f32x16 sS = (f32x16)(0.0f);
            const int key = kb*32 + qcol;
            const int rb  = key*256;
            const int sw  = (key&7) << 4;
            #pragma unroll
            for (int ks = 0; ks < 8; ++ks) {
                f16x8 kf = *(const f16x8*)(tile + rb + ((ks*32 + s*16) ^ sw));
                sS = __builtin_amdgcn_mfma_f32_32x32x16_f16(kf, qf[ks], sS, 0, 0, 0);
            }

            float pmax = fmaxf(fmaxf(fmaxf(sS[0], sS[1]), fmaxf(sS[2], sS[3])),
                               fmaxf(fmaxf(sS[4], sS[5]), fmaxf(sS[6], sS[7])));
            pmax = fmaxf(pmax,
                   fmaxf(fmaxf(fmaxf(sS[8], sS[9]), fmaxf(sS[10], sS[11])),
                         fmaxf(fmaxf(sS[12], sS[13]), fmaxf(sS[14], sS[15]))));
            pmax = fmaxf(pmax, __shfl_xor(pmax, 32));
            if (__any(pmax > m_run + 8.0f)) {
                const float mn = fmaxf(m_run, pmax);
                const float sc = __expf(m_run - mn);
                m_run = mn; l_run *= sc;
                #pragma unroll
                for (int ob = 0; ob < 8; ++ob)
                    #pragma unroll
                    for (int r = 0; r < 16; ++r) acc[ob][r] *= sc;
            }
            float p[16];
            float rs = 0.f;
            #pragma unroll
            for (int r = 0; r < 16; ++r) {
                p[r] = __expf(sS[r] - m_run);
                rs += p[r];
            }
            rs += __shfl_xor(rs, 32);
            l_run += rs;

            f16x8 pb0, pb1;
            #pragma unroll
            for (int ks2 = 0; ks2 < 2; ++ks2) {
                unsigned int pA0, pA1, pB0, pB1;
                if (ks2 == 0) {
                    pA0 = pk2(p[0], p[1]);  pA1 = pk2(p[2], p[3]);
                    pB0 = pk2(p[4], p[5]);  pB1 = pk2(p[6], p[7]);
                } else {
                    pA0 = pk2(p[8], p[9]);  pA1 = pk2(p[10], p[11]);
                    pB0 = pk2(p[12], p[13]); pB1 = pk2(p[14], p[15]);
                }
                const unsigned int lv0 = s ? pB0 : pA0;
                const unsigned int lv1 = s ? pB1 : pA1;
                const unsigned int sd0 = s ? pA0 : pB0;
                const unsigned int sd1 = s ? pA1 : pB1;
                const unsigned int rv0 = (unsigned int)__shfl_xor((int)sd0, 32);
                const unsigned int rv1 = (unsigned int)__shfl_xor((int)sd1, 32);
                union { unsigned int w[4]; f16x8 v; } u;
                u.w[0] = s ? rv0 : lv0;
                u.w[1] = s ? rv1 : lv1;
                u.w[2] = s ? lv0 : rv0;
                u.w[3] = s ? lv1 : rv1;
                if (ks2 == 0) pb0 = u.v; else pb1 = u.v;
            }

            #pragma unroll
            for (int ks2 = 0; ks2 < 2; ++ks2) {
                const int colb = kb*64 + ks2*32 + s*16;
                const f16x8 pbx = ks2 ? pb1 : pb0;
                #pragma unroll
                for (int ob = 0; ob < 8; ++ob) {
                    const int o = ob*32 + qcol;
                    f16x8 vf = *(const f16x8*)(tile + 16384 + o*128 +
                                               (colb ^ ((o&7)<<4)));
                    acc[ob] = __builtin_amdgcn_mfma_f32_32x32x16_f16(vf, pbx, acc[ob], 0, 0, 0);
                }
            }
        }

        __syncthreads();
        if (it < 63) {
            const char* src = kvb + (size_t)(it+1) * TILE_B;
            #pragma unroll
            for (int i = 0; i < 12; ++i)
                gload16(src + ((i*256 + t) << 4), tile + ((i*256 + wv*64) << 4));
        }
    }

    const float ga   = gamma[0];
    const float invl = 1.0f / l_run;
    const int n = m0 + wv*32 + qcol;
    #pragma unroll
    for (int ob = 0; ob < 8; ++ob) {
        #pragma unroll
        for (int r = 0; r < 16; ++r) {
            const int o = ob*32 + (r&3) + 8*(r>>2) + 4*s;
            const size_t a = ((size_t)(bb*NC + o))*NN + n;
            outp[a] = fmaf(acc[ob][r]*invl, ga, yg[a]);
        }
    }
}

extern "C" void kernel_launch(void* const* d_in, const int* in_sizes, int n_in,
                              void* d_out, int out_size, void* d_ws, size_t ws_size,
                              hipStream_t stream) {
    (void)in_sizes; (void)n_in; (void)out_size; (void)ws_size;
    const float* x     = (const float*)d_in[0];
    const float* y     = (const float*)d_in[1];
    const float* Wq    = (const float*)d_in[2];
    const float* bq    = (const float*)d_in[3];
    const float* Wk    = (const float*)d_in[4];
    const float* bk    = (const float*)d_in[5];
    const float* Wv    = (const float*)d_in[6];
    const float* bv    = (const float*)d_in[7];
    const float* gamma = (const float*)d_in[8];
    float* out = (float*)d_out;

    unsigned short* Qf = (unsigned short*)d_ws;              // 16 MB f16
    char* KV = (char*)(Qf + (size_t)NB*NN*NC2);              // 48 MB tiles

    qkv_kernel<<<dim3(1024), dim3(256), 0, stream>>>(
        x, y, Wq, bq, Wk, bk, Wv, bv, Qf, KV);
    attn_kernel<<<dim3(512), dim3(256), 0, stream>>>(
        Qf, KV, y, gamma, out);
}

// Round 8
// 306.066 us; speedup vs baseline: 2.0593x; 1.0441x over previous
//
#include <hip/hip_runtime.h>
#include <stdint.h>

using f32x4  = __attribute__((ext_vector_type(4))) float;
using f32x16 = __attribute__((ext_vector_type(16))) float;
using f16x8  = __attribute__((ext_vector_type(8))) _Float16;

#define NB  16
#define NC  256
#define NC2 128
#define NN  4096
#define TILE_B 49152   // 48 KB per 64-key tile: K 16K (64x256B swz) + V 32K (256x128B swz)

__device__ __forceinline__ unsigned int pk2(float a, float b) {
    auto h = __builtin_amdgcn_cvt_pkrtz(a, b);   // __fp16 ext_vector(2)
    return __builtin_bit_cast(unsigned int, h);
}

__device__ __forceinline__ f16x8 pack8(f32x4 a, f32x4 b) {
    union { unsigned int w[4]; f16x8 v; } u;
    u.w[0] = pk2(a[0], a[1]); u.w[1] = pk2(a[2], a[3]);
    u.w[2] = pk2(b[0], b[1]); u.w[3] = pk2(b[2], b[3]);
    return u.v;
}

__device__ __forceinline__ void gload16(const void* g, void* l) {
    __builtin_amdgcn_global_load_lds(
        (const __attribute__((address_space(1))) unsigned int*)g,
        (__attribute__((address_space(3))) unsigned int*)l, 16, 0, 0);
}

// ---------------------------------------------------------------------------
// Phase 1: 1x1-conv projections as MFMA f16 GEMM, LDS-staged epilogue.
// (round-6 structure; K/Q row swizzle uses (row&15) — full 16-granule spread)
// ---------------------------------------------------------------------------
__global__ __launch_bounds__(256, 2) void qkv_kernel(
    const float* __restrict__ x, const float* __restrict__ y,
    const float* __restrict__ Wq, const float* __restrict__ bq,
    const float* __restrict__ Wk, const float* __restrict__ bk,
    const float* __restrict__ Wv, const float* __restrict__ bv,
    unsigned short* __restrict__ Qf, char* __restrict__ KV)
{
    __shared__ __align__(16) char lds[65536];

    const int bid   = blockIdx.x;
    const int ntile = bid & 63;
    const int bb    = bid >> 6;
    const int nblk  = ntile * 64;

    const int t    = threadIdx.x;
    const int lane = t & 63;
    const int wid  = t >> 6;
    const int l31  = lane & 31;
    const int s    = lane >> 5;

    // ---------------- pass 1: Q (waves 0-1) / K (waves 2-3) ----------------
    {
        const bool isQ = (wid < 2);
        const float* srcb = (isQ ? x : y) + (size_t)bb * NC * NN;
        const float* W    = isQ ? Wq : Wk;
        const float* bias = isQ ? bq : bk;
        const int wo = (wid & 1) * 64;
        const int base = isQ ? 49152 : 0;

        f32x16 acc[2][2];
        #pragma unroll
        for (int a = 0; a < 2; ++a)
            #pragma unroll
            for (int bc = 0; bc < 2; ++bc) acc[a][bc] = (f32x16)(0.0f);

        #pragma unroll 4
        for (int ks = 0; ks < 16; ++ks) {
            const int c0 = ks * 16 + s * 8;
            f16x8 wf[2], xf[2];
            #pragma unroll
            for (int a = 0; a < 2; ++a) {
                const float* wr = W + (size_t)(wo + a * 32 + l31) * NC + c0;
                wf[a] = pack8(*(const f32x4*)wr, *(const f32x4*)(wr + 4));
            }
            #pragma unroll
            for (int bc = 0; bc < 2; ++bc) {
                const float* xc = srcb + (size_t)c0 * NN + nblk + bc * 32 + l31;
                f32x4 v0, v1;
                v0[0] = xc[0*NN]; v0[1] = xc[1*NN]; v0[2] = xc[2*NN]; v0[3] = xc[3*NN];
                v1[0] = xc[4*NN]; v1[1] = xc[5*NN]; v1[2] = xc[6*NN]; v1[3] = xc[7*NN];
                xf[bc] = pack8(v0, v1);
            }
            #pragma unroll
            for (int a = 0; a < 2; ++a)
                #pragma unroll
                for (int bc = 0; bc < 2; ++bc)
                    acc[a][bc] = __builtin_amdgcn_mfma_f32_32x32x16_f16(
                        wf[a], xf[bc], acc[a][bc], 0, 0, 0);
        }

        #pragma unroll
        for (int a = 0; a < 2; ++a) {
            #pragma unroll
            for (int bc = 0; bc < 2; ++bc) {
                const int nr = bc * 32 + l31;
                #pragma unroll
                for (int g = 0; g < 4; ++g) {
                    const int o0 = wo + a * 32 + 8 * g + 4 * s;
                    const f32x4 bv4 = *(const f32x4*)(bias + o0);
                    union { unsigned int w[2]; uint2 u2; } pk;
                    pk.w[0] = pk2(acc[a][bc][g*4+0] + bv4[0], acc[a][bc][g*4+1] + bv4[1]);
                    pk.w[1] = pk2(acc[a][bc][g*4+2] + bv4[2], acc[a][bc][g*4+3] + bv4[3]);
                    const int dst = base + nr*256 +
                        (((o0 >> 3) << 4) ^ ((nr & 15) << 4)) + (o0 & 7) * 2;
                    *(uint2*)(lds + dst) = pk.u2;
                }
            }
        }
    }

    // ---------------- pass 2: V (all waves, swapped mfma) ----------------
    {
        const float* srcb = y + (size_t)bb * NC * NN;
        const int wo = wid * 64;

        f32x16 acc[2][2];
        #pragma unroll
        for (int a = 0; a < 2; ++a)
            #pragma unroll
            for (int bc = 0; bc < 2; ++bc) acc[a][bc] = (f32x16)(0.0f);

        #pragma unroll 4
        for (int ks = 0; ks < 16; ++ks) {
            const int c0 = ks * 16 + s * 8;
            f16x8 wf[2], xf[2];
            #pragma unroll
            for (int a = 0; a < 2; ++a) {
                const float* wr = Wv + (size_t)(wo + a * 32 + l31) * NC + c0;
                wf[a] = pack8(*(const f32x4*)wr, *(const f32x4*)(wr + 4));
            }
            #pragma unroll
            for (int bc = 0; bc < 2; ++bc) {
                const float* xc = srcb + (size_t)c0 * NN + nblk + bc * 32 + l31;
                f32x4 v0, v1;
                v0[0] = xc[0*NN]; v0[1] = xc[1*NN]; v0[2] = xc[2*NN]; v0[3] = xc[3*NN];
                v1[0] = xc[4*NN]; v1[1] = xc[5*NN]; v1[2] = xc[6*NN]; v1[3] = xc[7*NN];
                xf[bc] = pack8(v0, v1);
            }
            #pragma unroll
            for (int a = 0; a < 2; ++a)
                #pragma unroll
                for (int bc = 0; bc < 2; ++bc)
                    acc[a][bc] = __builtin_amdgcn_mfma_f32_32x32x16_f16(
                        xf[bc], wf[a], acc[a][bc], 0, 0, 0);
        }

        #pragma unroll
        for (int a = 0; a < 2; ++a) {
            const int o = wo + a * 32 + l31;
            const float bvo = bv[o];
            #pragma unroll
            for (int bc = 0; bc < 2; ++bc) {
                #pragma unroll
                for (int g = 0; g < 4; ++g) {
                    const int nr = bc * 32 + 8 * g + 4 * s;
                    union { unsigned int w[2]; uint2 u2; } pk;
                    pk.w[0] = pk2(acc[a][bc][g*4+0] + bvo, acc[a][bc][g*4+1] + bvo);
                    pk.w[1] = pk2(acc[a][bc][g*4+2] + bvo, acc[a][bc][g*4+3] + bvo);
                    const int dst = 16384 + o*128 +
                        (((nr >> 3) << 4) ^ ((o & 7) << 4)) + (nr & 7) * 2;
                    *(uint2*)(lds + dst) = pk.u2;
                }
            }
        }
    }

    __syncthreads();

    // ---------------- coalesced copy-out ----------------
    char* kvt = KV + (size_t)(bb*64 + ntile) * TILE_B;
    #pragma unroll
    for (int i = 0; i < 12; ++i) {
        const int off = (i*256 + t) * 16;
        *(uint4*)(kvt + off) = *(const uint4*)(lds + off);
    }
    char* qg = (char*)Qf + ((size_t)(bb*NN + nblk)) * NC2 * 2;
    #pragma unroll
    for (int i = 0; i < 4; ++i) {
        const int g = (i*256 + t) * 16;
        const int sidx = 49152 + (g ^ (((g >> 8) & 15) << 4));
        *(uint4*)(qg + g) = *(const uint4*)(lds + sidx);
    }
}

// ---------------------------------------------------------------------------
// Phase 2: flash attention, phase-split pipeline with counted vmcnt.
// K double-buffered (2x16K), V single (32K) = 64 KB LDS, 2 blocks/CU.
// Per iter: vmcnt(8)+bar -> QK(64 keys) -> issue K(t+1) -> JOINT softmax over
// all 64 keys (single max/rescale; both P halves packed against the SAME
// m_run -> no stale-max race with PV) -> vmcnt(4)+bar -> PV -> bar ->
// issue V(t+1).
// ---------------------------------------------------------------------------
__global__ __launch_bounds__(256, 2) void attn_kernel(
    const unsigned short* __restrict__ Qf, const char* __restrict__ KV,
    const float* __restrict__ yg, const float* __restrict__ gamma,
    float* __restrict__ outp)
{
    __shared__ __align__(16) char kls[2][16384];
    __shared__ __align__(16) char vls[32768];

    const int bid = ((blockIdx.x & 7) << 6) + (blockIdx.x >> 3);
    const int bb = bid >> 5;
    const int m0 = (bid & 31) * 128;
    const int t    = threadIdx.x;
    const int lane = t & 63;
    const int wv   = t >> 6;
    const int qcol = lane & 31;
    const int s    = lane >> 5;

    f16x8 qf[8];
    {
        const char* qrow = (const char*)Qf +
            (((size_t)bb*NN + m0 + wv*32 + qcol) * NC2) * 2;
        #pragma unroll
        for (int ks = 0; ks < 8; ++ks)
            qf[ks] = *(const f16x8*)(qrow + ks*32 + s*16);
    }

    f32x16 acc[8];
    #pragma unroll
    for (int ob = 0; ob < 8; ++ob) acc[ob] = (f32x16)(0.0f);
    float m_run = -3.0e38f, l_run = 0.0f;

    const char* kvb = KV + (size_t)bb * 64 * TILE_B;

    // prologue: K(0) [4 loads], V(0) [8 loads] -> 12 outstanding
    #pragma unroll
    for (int i = 0; i < 4; ++i)
        gload16(kvb + ((i*256 + t) << 4), kls[0] + ((i*256 + wv*64) << 4));
    #pragma unroll
    for (int i = 0; i < 8; ++i)
        gload16(kvb + 16384 + ((i*256 + t) << 4), vls + ((i*256 + wv*64) << 4));

    #pragma unroll 1
    for (int it = 0; it < 64; ++it) {
        // K(it) retired (V(it) 8 loads still outstanding)
        asm volatile("s_waitcnt vmcnt(8)" ::: "memory");
        __builtin_amdgcn_s_barrier();
        asm volatile("" ::: "memory");

        const char* kbuf = kls[it & 1];
        const char* nsrc = kvb + (size_t)((it + 1) & 63) * TILE_B;

        // --- QK over all 64 keys (two 32-key halves) ---
        f32x16 sA = (f32x16)(0.0f), sB = (f32x16)(0.0f);
        {
            const int keyA = qcol, keyB = 32 + qcol;
            const int rbA = keyA * 256, rbB = keyB * 256;
            const int swA = (keyA & 15) << 4, swB = (keyB & 15) << 4;
            __builtin_amdgcn_s_setprio(1);
            #pragma unroll
            for (int ks = 0; ks < 8; ++ks) {
                f16x8 kf = *(const f16x8*)(kbuf + rbA + ((ks*32 + s*16) ^ swA));
                sA = __builtin_amdgcn_mfma_f32_32x32x16_f16(kf, qf[ks], sA, 0, 0, 0);
            }
            #pragma unroll
            for (int ks = 0; ks < 8; ++ks) {
                f16x8 kf = *(const f16x8*)(kbuf + rbB + ((ks*32 + s*16) ^ swB));
                sB = __builtin_amdgcn_mfma_f32_32x32x16_f16(kf, qf[ks], sB, 0, 0, 0);
            }
            __builtin_amdgcn_s_setprio(0);
        }

        // --- prefetch K(it+1) into the other K buffer ---
        {
            char* kdst = (char*)kls[(it + 1) & 1];
            #pragma unroll
            for (int i = 0; i < 4; ++i)
                gload16(nsrc + ((i*256 + t) << 4), kdst + ((i*256 + wv*64) << 4));
        }

        // --- JOINT online softmax over all 64 keys ---
        f16x8 pfr[2][2];
        {
            float pmax = -3.0e38f;
            #pragma unroll
            for (int r = 0; r < 16; ++r) pmax = fmaxf(pmax, sA[r]);
            #pragma unroll
            for (int r = 0; r < 16; ++r) pmax = fmaxf(pmax, sB[r]);
            pmax = fmaxf(pmax, __shfl_xor(pmax, 32));
            if (__any(pmax > m_run + 8.0f)) {       // T13 defer-max
                const float mn = fmaxf(m_run, pmax);
                const float sc = __expf(m_run - mn);
                m_run = mn; l_run *= sc;
                #pragma unroll
                for (int ob = 0; ob < 8; ++ob)
                    #pragma unroll
                    for (int r = 0; r < 16; ++r) acc[ob][r] *= sc;
            }
            float pa[16], pb[16];
            float rs = 0.f;
            #pragma unroll
            for (int r = 0; r < 16; ++r) { pa[r] = __expf(sA[r] - m_run); rs += pa[r]; }
            #pragma unroll
            for (int r = 0; r < 16; ++r) { pb[r] = __expf(sB[r] - m_run); rs += pb[r]; }
            rs += __shfl_xor(rs, 32);
            l_run += rs;

            #pragma unroll
            for (int kb = 0; kb < 2; ++kb) {
                #pragma unroll
                for (int ks2 = 0; ks2 < 2; ++ks2) {
                    unsigned int pA0, pA1, pB0, pB1;
                    if (kb == 0) {
                        if (ks2 == 0) {
                            pA0 = pk2(pa[0], pa[1]);  pA1 = pk2(pa[2], pa[3]);
                            pB0 = pk2(pa[4], pa[5]);  pB1 = pk2(pa[6], pa[7]);
                        } else {
                            pA0 = pk2(pa[8], pa[9]);  pA1 = pk2(pa[10], pa[11]);
                            pB0 = pk2(pa[12], pa[13]); pB1 = pk2(pa[14], pa[15]);
                        }
                    } else {
                        if (ks2 == 0) {
                            pA0 = pk2(pb[0], pb[1]);  pA1 = pk2(pb[2], pb[3]);
                            pB0 = pk2(pb[4], pb[5]);  pB1 = pk2(pb[6], pb[7]);
                        } else {
                            pA0 = pk2(pb[8], pb[9]);  pA1 = pk2(pb[10], pb[11]);
                            pB0 = pk2(pb[12], pb[13]); pB1 = pk2(pb[14], pb[15]);
                        }
                    }
                    const unsigned int lv0 = s ? pB0 : pA0;
                    const unsigned int lv1 = s ? pB1 : pA1;
                    const unsigned int sd0 = s ? pA0 : pB0;
                    const unsigned int sd1 = s ? pA1 : pB1;
                    const unsigned int rv0 = (unsigned int)__shfl_xor((int)sd0, 32);
                    const unsigned int rv1 = (unsigned int)__shfl_xor((int)sd1, 32);
                    union { unsigned int w[4]; f16x8 v; } u;
                    u.w[0] = s ? rv0 : lv0;
                    u.w[1] = s ? rv1 : lv1;
                    u.w[2] = s ? lv0 : rv0;
                    u.w[3] = s ? lv1 : rv1;
                    pfr[kb][ks2] = u.v;
                }
            }
        }

        // --- V(it) retired (K(it+1) 4 loads still outstanding) ---
        asm volatile("s_waitcnt vmcnt(4)" ::: "memory");
        __builtin_amdgcn_s_barrier();
        asm volatile("" ::: "memory");

        // --- PV: acc[o][q] += V[o][key] * P^T ---
        __builtin_amdgcn_s_setprio(1);
        #pragma unroll
        for (int kb = 0; kb < 2; ++kb) {
            #pragma unroll
            for (int ks2 = 0; ks2 < 2; ++ks2) {
                const int colb = kb*64 + ks2*32 + s*16;
                const f16x8 pbx = pfr[kb][ks2];
                #pragma unroll
                for (int ob = 0; ob < 8; ++ob) {
                    const int o = ob*32 + qcol;
                    f16x8 vf = *(const f16x8*)(vls + o*128 + (colb ^ ((o&7)<<4)));
                    acc[ob] = __builtin_amdgcn_mfma_f32_32x32x16_f16(vf, pbx, acc[ob], 0, 0, 0);
                }
            }
        }
        __builtin_amdgcn_s_setprio(0);

        asm volatile("" ::: "memory");
        __builtin_amdgcn_s_barrier();   // all waves done reading V(it)
        asm volatile("" ::: "memory");

        // --- prefetch V(it+1) ---
        #pragma unroll
        for (int i = 0; i < 8; ++i)
            gload16(nsrc + 16384 + ((i*256 + t) << 4), vls + ((i*256 + wv*64) << 4));
    }
    asm volatile("s_waitcnt vmcnt(0)" ::: "memory");

    // --- epilogue: out[o][n] = gamma * acc/l + y ---
    const float ga   = gamma[0];
    const float invl = 1.0f / l_run;
    const int n = m0 + wv*32 + qcol;
    #pragma unroll
    for (int ob = 0; ob < 8; ++ob) {
        #pragma unroll
        for (int r = 0; r < 16; ++r) {
            const int o = ob*32 + (r&3) + 8*(r>>2) + 4*s;
            const size_t a = ((size_t)(bb*NC + o))*NN + n;
            outp[a] = fmaf(acc[ob][r]*invl, ga, yg[a]);
        }
    }
}

extern "C" void kernel_launch(void* const* d_in, const int* in_sizes, int n_in,
                              void* d_out, int out_size, void* d_ws, size_t ws_size,
                              hipStream_t stream) {
    (void)in_sizes; (void)n_in; (void)out_size; (void)ws_size;
    const float* x     = (const float*)d_in[0];
    const float* y     = (const float*)d_in[1];
    const float* Wq    = (const float*)d_in[2];
    const float* bq    = (const float*)d_in[3];
    const float* Wk    = (const float*)d_in[4];
    const float* bk    = (const float*)d_in[5];
    const float* Wv    = (const float*)d_in[6];
    const float* bv    = (const float*)d_in[7];
    const float* gamma = (const float*)d_in[8];
    float* out = (float*)d_out;

    unsigned short* Qf = (unsigned short*)d_ws;              // 16 MB f16
    char* KV = (char*)(Qf + (size_t)NB*NN*NC2);              // 48 MB tiles

    qkv_kernel<<<dim3(1024), dim3(256), 0, stream>>>(
        x, y, Wq, bq, Wk, bk, Wv, bv, Qf, KV);
    attn_kernel<<<dim3(512), dim3(256), 0, stream>>>(
        Qf, KV, y, gamma, out);
}